// Round 1
// baseline (101.358 us; speedup 1.0000x reference)
//
#include <hip/hip_runtime.h>
#include <cmath>

// Problem constants
#define BROWS 32768
#define SLEN  1024
#define TAILW 195
#define NB    2048   // blocks for row kernel (4 waves each -> 8192 waves, 4 rows/wave)

__device__ __constant__ float c_decay_taus[4] = {40.0f, 300.0f, 230.0f, 2.4f};
__device__ __constant__ float c_rise_taus[4]  = {5.0f, 20.0f, 10.0f, 2.0f};

// One wave (64 lanes) processes one row at a time; row cached in 16 regs/lane.
extern "C" __global__ __launch_bounds__(256)
void physics_rows(const float* __restrict__ logits,
                  const int* __restrict__ labels,
                  const float* __restrict__ wave,
                  const float* __restrict__ amps,
                  double* __restrict__ partials)
{
    const int lane = threadIdx.x & 63;
    const int wid  = threadIdx.x >> 6;            // wave id within block (0..3)
    const int gwave  = blockIdx.x * 4 + wid;
    const int nwaves = gridDim.x * 4;

    // per-wave (lane0-held) accumulators, all f64
    double a_ce = 0.0, a_tau = 0.0, a_tc = 0.0;
    double a_rs = 0.0, a_rc = 0.0, a_r1 = 0.0, a_r2 = 0.0;

    for (int row = gwave; row < BROWS; row += nwaves) {
        const float4* wrow = reinterpret_cast<const float4*>(wave) + (size_t)row * (SLEN / 4);
        float4 q0 = wrow[lane];
        float4 q1 = wrow[64 + lane];
        float4 q2 = wrow[128 + lane];
        float4 q3 = wrow[192 + lane];
        float vals[16] = {q0.x,q0.y,q0.z,q0.w, q1.x,q1.y,q1.z,q1.w,
                          q2.x,q2.y,q2.z,q2.w, q3.x,q3.y,q3.z,q3.w};

        // ---- pass 1: charge sum + argmax (first occurrence) ----
        float bm = -INFINITY; int bj = SLEN;
        double csum = 0.0;
        #pragma unroll
        for (int k = 0; k < 16; ++k) {
            const int j = (k >> 2) * 256 + lane * 4 + (k & 3);  // element index in row
            const float w = vals[k];
            csum += (double)fmaxf(w, 0.0f);
            if (w > bm) { bm = w; bj = j; }   // strict > keeps lowest j within lane
        }
        #pragma unroll
        for (int off = 1; off < 64; off <<= 1) {
            float ov = __shfl_xor(bm, off, 64);
            int   oj = __shfl_xor(bj, off, 64);
            if (ov > bm || (ov == bm && oj < bj)) { bm = ov; bj = oj; }
        }
        #pragma unroll
        for (int off = 1; off < 64; off <<= 1) csum += __shfl_xor(csum, off, 64);

        const int   peak = bj;   // identical on all lanes
        const float amp  = bm;

        // ---- pass 2: decay-tail regression sums (f64) ----
        double n = 0.0, St = 0.0, Sy = 0.0, Sty = 0.0, Stt = 0.0;
        if (peak < SLEN - 20) {               // wave-uniform branch
            #pragma unroll
            for (int k = 0; k < 16; ++k) {
                const int j  = (k >> 2) * 256 + lane * 4 + (k & 3);
                const int kk = j - peak - 5;  // window offset
                const float w = vals[k];
                if (kk >= 0 && kk < TAILW && w > 0.0f) {
                    const double t = (double)kk * 8.0;           // DT_NS
                    const double y = log((double)w + 1e-8);
                    n += 1.0; St += t; Sy += y; Sty += t * y; Stt += t * t;
                }
            }
            #pragma unroll
            for (int off = 1; off < 64; off <<= 1) {
                n   += __shfl_xor(n,   off, 64);
                St  += __shfl_xor(St,  off, 64);
                Sy  += __shfl_xor(Sy,  off, 64);
                Sty += __shfl_xor(Sty, off, 64);
                Stt += __shfl_xor(Stt, off, 64);
            }
        }

        // ---- pass 3: rise-time first crossings ----
        int i10 = SLEN, i90 = SLEN;
        const float t10 = 0.1f * amp, t90 = 0.9f * amp;
        #pragma unroll
        for (int k = 0; k < 16; ++k) {
            const int j = (k >> 2) * 256 + lane * 4 + (k & 3);
            const float w = vals[k];
            if (j < peak) {
                if (w >= t10 && j < i10) i10 = j;
                if (w >= t90 && j < i90) i90 = j;
            }
        }
        #pragma unroll
        for (int off = 1; off < 64; off <<= 1) {
            i10 = min(i10, __shfl_xor(i10, off, 64));
            i90 = min(i90, __shfl_xor(i90, off, 64));
        }

        // ---- lane 0: scalar epilogue for this row ----
        if (lane == 0) {
            // CE + predicted class
            const float4 l4 = reinterpret_cast<const float4*>(logits)[row];
            float lg[4] = {l4.x, l4.y, l4.z, l4.w};
            int pred = 0; float pbest = lg[0];
            #pragma unroll
            for (int c = 1; c < 4; ++c) if (lg[c] > pbest) { pbest = lg[c]; pred = c; }
            const float m = fmaxf(fmaxf(lg[0], lg[1]), fmaxf(lg[2], lg[3]));
            const double sexp = exp((double)lg[0] - (double)m) + exp((double)lg[1] - (double)m)
                              + exp((double)lg[2] - (double)m) + exp((double)lg[3] - (double)m);
            const double lse = (double)m + log(sexp);
            const int lb = labels[row];
            a_ce += lse - (double)lg[lb];

            // decay loss
            if (peak < SLEN - 20 && n >= 5.0) {
                const double num = Sty - St * Sy / n;
                const double den = Stt - St * St / n;
                if (den > 0.0) {
                    const double slope = num / fmax(den, 1e-30);
                    const double tau   = -1.0 / (slope + 1e-8);
                    const double d     = tau - (double)c_decay_taus[pred];
                    a_tau += d * d; a_tc += 1.0;
                }
            }
            // rise loss
            if (peak >= 10 && i10 < SLEN && i90 < SLEN) {
                const double rise = (double)(i90 - i10) * 8.0;
                const double er   = (double)c_rise_taus[pred];
                a_rs += fabs(rise - er) / er; a_rc += 1.0;
            }
            // energy ratio moments
            const double ratio = csum / ((double)amps[row] + 1e-8);
            a_r1 += ratio; a_r2 += ratio * ratio;
        }
    }

    // ---- block reduction -> per-block partials (no atomics, all slots written) ----
    __shared__ double sm[4][8];
    if (lane == 0) {
        sm[wid][0] = a_ce;  sm[wid][1] = a_tau; sm[wid][2] = a_tc;
        sm[wid][3] = a_rs;  sm[wid][4] = a_rc;  sm[wid][5] = a_r1; sm[wid][6] = a_r2;
    }
    __syncthreads();
    if (threadIdx.x < 7) {
        const int i = threadIdx.x;
        partials[(size_t)blockIdx.x * 7 + i] = sm[0][i] + sm[1][i] + sm[2][i] + sm[3][i];
    }
}

extern "C" __global__ __launch_bounds__(256)
void physics_finalize(const double* __restrict__ partials, float* __restrict__ out)
{
    __shared__ double sm[256];
    __shared__ double tot[7];
    double loc[7] = {0, 0, 0, 0, 0, 0, 0};
    for (int b = threadIdx.x; b < NB; b += 256) {
        #pragma unroll
        for (int i = 0; i < 7; ++i) loc[i] += partials[(size_t)b * 7 + i];
    }
    for (int i = 0; i < 7; ++i) {
        sm[threadIdx.x] = loc[i];
        __syncthreads();
        for (int s = 128; s > 0; s >>= 1) {
            if (threadIdx.x < s) sm[threadIdx.x] += sm[threadIdx.x + s];
            __syncthreads();
        }
        if (threadIdx.x == 0) tot[i] = sm[0];
        __syncthreads();
    }
    if (threadIdx.x == 0) {
        const double Bn = (double)BROWS;
        const double ce    = tot[0] / Bn;
        const double decay = (tot[2] > 0.0) ? tot[1] / fmax(tot[2], 1.0) : 0.0;
        const double rise  = (tot[4] > 0.0) ? tot[3] / fmax(tot[4], 1.0) : 0.0;
        const double var   = (tot[6] - tot[5] * tot[5] / Bn) / (Bn - 1.0);  // ddof=1
        const double total = 0.7 * ce + 0.2 * decay + 0.1 * var + 0.05 * rise;
        out[0] = (float)total; out[1] = (float)ce; out[2] = (float)decay;
        out[3] = (float)var;   out[4] = (float)rise;
    }
}

extern "C" void kernel_launch(void* const* d_in, const int* in_sizes, int n_in,
                              void* d_out, int out_size, void* d_ws, size_t ws_size,
                              hipStream_t stream) {
    const float* logits = (const float*)d_in[0];
    const int*   labels = (const int*)d_in[1];
    const float* wave   = (const float*)d_in[2];
    const float* amps   = (const float*)d_in[3];
    double* partials = (double*)d_ws;   // NB*7 doubles = 114,688 bytes

    physics_rows<<<NB, 256, 0, stream>>>(logits, labels, wave, amps, partials);
    physics_finalize<<<1, 256, 0, stream>>>(partials, (float*)d_out);
}

// Round 2
// 59.330 us; speedup vs baseline: 1.7084x; 1.7084x over previous
//
#include <hip/hip_runtime.h>
#include <cmath>

// Problem constants
#define BROWS 32768
#define SLEN  1024
#define TAILW 195
#define NB    2048   // blocks for row kernel (4 waves each -> 8192 waves, 4 rows/wave)

__device__ __constant__ float c_decay_taus[4] = {40.0f, 300.0f, 230.0f, 2.4f};
__device__ __constant__ float c_rise_taus[4]  = {5.0f, 20.0f, 10.0f, 2.0f};

// One wave (64 lanes) processes one row at a time; row cached in 16 regs/lane.
// f64 kept ONLY where cancellation matters (Sy, Sky accumulation + final
// slope/tau/variance combine); everything else f32 (log/exp use HW v_log_f32 /
// v_exp_f32). n / Sum(kk) / Sum(kk^2) are integer-valued and exact in f32.
extern "C" __global__ __launch_bounds__(256)
void physics_rows(const float* __restrict__ logits,
                  const int* __restrict__ labels,
                  const float* __restrict__ wave,
                  const float* __restrict__ amps,
                  double* __restrict__ partials)
{
    const int lane = threadIdx.x & 63;
    const int wid  = threadIdx.x >> 6;            // wave id within block (0..3)
    const int gwave  = blockIdx.x * 4 + wid;
    const int nwaves = gridDim.x * 4;
    const int lane4  = lane * 4;

    // per-wave (lane0-held) accumulators, f64
    double a_ce = 0.0, a_tau = 0.0, a_tc = 0.0;
    double a_rs = 0.0, a_rc = 0.0, a_r1 = 0.0, a_r2 = 0.0;

    for (int row = gwave; row < BROWS; row += nwaves) {
        const float4* wrow = reinterpret_cast<const float4*>(wave) + (size_t)row * (SLEN / 4);
        float4 q0 = wrow[lane];
        float4 q1 = wrow[64 + lane];
        float4 q2 = wrow[128 + lane];
        float4 q3 = wrow[192 + lane];
        float vals[16] = {q0.x,q0.y,q0.z,q0.w, q1.x,q1.y,q1.z,q1.w,
                          q2.x,q2.y,q2.z,q2.w, q3.x,q3.y,q3.z,q3.w};

        // ---- pass 1: charge sum (f32) + argmax (first occurrence) ----
        float bm = -INFINITY; int bj = SLEN;
        float csum = 0.0f;
        #pragma unroll
        for (int k = 0; k < 16; ++k) {
            const int j = (k >> 2) * 256 + lane4 + (k & 3);   // element index
            const float w = vals[k];
            csum += fmaxf(w, 0.0f);
            if (w > bm) { bm = w; bj = j; }   // strict > keeps lowest j (j increases with k)
        }
        #pragma unroll
        for (int off = 1; off < 64; off <<= 1) {
            float ov = __shfl_xor(bm, off, 64);
            int   oj = __shfl_xor(bj, off, 64);
            if (ov > bm || (ov == bm && oj < bj)) { bm = ov; bj = oj; }
            csum += __shfl_xor(csum, off, 64);
        }

        const int   peak = bj;   // identical on all lanes
        const float amp  = bm;
        const bool  do_decay = (peak < SLEN - 20);

        // ---- pass 2 (fused): decay-tail regression sums + rise crossings ----
        float  n = 0.0f, Sk = 0.0f, Skk = 0.0f;      // exact (integer-valued)
        double Sy = 0.0, Sky = 0.0;                  // need f64 accumulation
        int i10 = SLEN, i90 = SLEN;
        const float t10 = 0.1f * amp, t90 = 0.9f * amp;
        const int pm5 = peak + 5;
        #pragma unroll
        for (int k = 0; k < 16; ++k) {
            const int j = (k >> 2) * 256 + lane4 + (k & 3);
            const float w = vals[k];
            // decay window
            const int kk = j - pm5;
            if (do_decay && (unsigned)kk < (unsigned)TAILW && w > 0.0f) {
                const float fk = (float)kk;
                const float y  = logf(w + 1e-8f);    // f32 HW log (jax does f32 too)
                n  += 1.0f;
                Sk += fk;
                Skk = fmaf(fk, fk, Skk);
                Sy  += (double)y;
                Sky += (double)(fk) * (double)y;
            }
            // rising edge
            if (j < peak) {
                if (w >= t10 && j < i10) i10 = j;
                if (w >= t90 && j < i90) i90 = j;
            }
        }
        #pragma unroll
        for (int off = 1; off < 64; off <<= 1) {
            n   += __shfl_xor(n,   off, 64);
            Sk  += __shfl_xor(Sk,  off, 64);
            Skk += __shfl_xor(Skk, off, 64);
            Sy  += __shfl_xor(Sy,  off, 64);
            Sky += __shfl_xor(Sky, off, 64);
            i10 = min(i10, __shfl_xor(i10, off, 64));
            i90 = min(i90, __shfl_xor(i90, off, 64));
        }

        // ---- lane 0: scalar epilogue for this row ----
        if (lane == 0) {
            // CE + predicted class (all f32; value is O(1), huge headroom)
            const float4 l4 = reinterpret_cast<const float4*>(logits)[row];
            float lg[4] = {l4.x, l4.y, l4.z, l4.w};
            int pred = 0; float pbest = lg[0];
            #pragma unroll
            for (int c = 1; c < 4; ++c) if (lg[c] > pbest) { pbest = lg[c]; pred = c; }
            const float m = fmaxf(fmaxf(lg[0], lg[1]), fmaxf(lg[2], lg[3]));
            const float sexp = expf(lg[0] - m) + expf(lg[1] - m)
                             + expf(lg[2] - m) + expf(lg[3] - m);
            const float lse = m + logf(sexp);
            const int lb = labels[row];
            a_ce += (double)(lse - lg[lb]);

            // decay loss (f64 combine: slope/tau are cancellation-sensitive)
            if (do_decay && n >= 5.0f) {
                const double dn  = (double)n;
                const double dSk = (double)Sk;
                const double num = Sky - dSk * Sy / dn;              // / DT_NS factored
                const double den = 8.0 * ((double)Skk - dSk * dSk / dn);
                if (den > 0.0) {
                    const double slope = num / fmax(den, 1e-30);
                    const double tau   = -1.0 / (slope + 1e-8);
                    const double d     = tau - (double)c_decay_taus[pred];
                    a_tau += d * d; a_tc += 1.0;
                }
            }
            // rise loss
            if (peak >= 10 && i10 < SLEN && i90 < SLEN) {
                const float rise = (float)(i90 - i10) * 8.0f;
                const float er   = c_rise_taus[pred];
                a_rs += (double)(fabsf(rise - er) / er); a_rc += 1.0;
            }
            // energy ratio moments (f64 accumulation for the variance combine)
            const double ratio = (double)csum / ((double)amps[row] + 1e-8);
            a_r1 += ratio; a_r2 += ratio * ratio;
        }
    }

    // ---- block reduction -> per-block partials (no atomics, all slots written) ----
    __shared__ double sm[4][8];
    if (lane == 0) {
        sm[wid][0] = a_ce;  sm[wid][1] = a_tau; sm[wid][2] = a_tc;
        sm[wid][3] = a_rs;  sm[wid][4] = a_rc;  sm[wid][5] = a_r1; sm[wid][6] = a_r2;
    }
    __syncthreads();
    if (threadIdx.x < 7) {
        const int i = threadIdx.x;
        partials[(size_t)blockIdx.x * 7 + i] = sm[0][i] + sm[1][i] + sm[2][i] + sm[3][i];
    }
}

extern "C" __global__ __launch_bounds__(256)
void physics_finalize(const double* __restrict__ partials, float* __restrict__ out)
{
    __shared__ double sm[256];
    __shared__ double tot[7];
    double loc[7] = {0, 0, 0, 0, 0, 0, 0};
    for (int b = threadIdx.x; b < NB; b += 256) {
        #pragma unroll
        for (int i = 0; i < 7; ++i) loc[i] += partials[(size_t)b * 7 + i];
    }
    for (int i = 0; i < 7; ++i) {
        sm[threadIdx.x] = loc[i];
        __syncthreads();
        for (int s = 128; s > 0; s >>= 1) {
            if (threadIdx.x < s) sm[threadIdx.x] += sm[threadIdx.x + s];
            __syncthreads();
        }
        if (threadIdx.x == 0) tot[i] = sm[0];
        __syncthreads();
    }
    if (threadIdx.x == 0) {
        const double Bn = (double)BROWS;
        const double ce    = tot[0] / Bn;
        const double decay = (tot[2] > 0.0) ? tot[1] / fmax(tot[2], 1.0) : 0.0;
        const double rise  = (tot[4] > 0.0) ? tot[3] / fmax(tot[4], 1.0) : 0.0;
        const double var   = (tot[6] - tot[5] * tot[5] / Bn) / (Bn - 1.0);  // ddof=1
        const double total = 0.7 * ce + 0.2 * decay + 0.1 * var + 0.05 * rise;
        out[0] = (float)total; out[1] = (float)ce; out[2] = (float)decay;
        out[3] = (float)var;   out[4] = (float)rise;
    }
}

extern "C" void kernel_launch(void* const* d_in, const int* in_sizes, int n_in,
                              void* d_out, int out_size, void* d_ws, size_t ws_size,
                              hipStream_t stream) {
    const float* logits = (const float*)d_in[0];
    const int*   labels = (const int*)d_in[1];
    const float* wave   = (const float*)d_in[2];
    const float* amps   = (const float*)d_in[3];
    double* partials = (double*)d_ws;   // NB*7 doubles = 114,688 bytes

    physics_rows<<<NB, 256, 0, stream>>>(logits, labels, wave, amps, partials);
    physics_finalize<<<1, 256, 0, stream>>>(partials, (float*)d_out);
}

// Round 3
// 54.459 us; speedup vs baseline: 1.8612x; 1.0895x over previous
//
#include <hip/hip_runtime.h>
#include <cmath>

// Problem constants
#define BROWS 32768
#define SLEN  1024
#define TAILW 195
#define NB1   2048   // kernel1: 2048 blocks x 4 waves = 8192 waves, 4 rows/wave
#define NB2   128    // kernel2: 128 blocks x 256 threads, 1 row/thread

__device__ __constant__ float c_decay_taus[4] = {40.0f, 300.0f, 230.0f, 2.4f};
__device__ __constant__ float c_rise_taus[4]  = {5.0f, 20.0f, 10.0f, 2.0f};

// Per-row stats, 32 B. n<=195 (16b), Sk<=18915 (16b), Skk<=2451415 (exact u32),
// peak<=1023 (10b), i10/i90<=1024 (11b each).
struct alignas(16) RowStat {
    unsigned nSk;   // n | (Sk<<16)
    unsigned Skk;
    float    csum;
    unsigned pki;   // (peak<<22)|(i10<<11)|i90
    double   Sy;
    double   Sky;
};

// Kernel 1: waveform-only. One wave per row, row in 16 regs/lane, 1-row-ahead
// software prefetch. No divergent epilogue, no scalar side-loads.
extern "C" __global__ __launch_bounds__(256, 8)
void physics_rows(const float* __restrict__ wave, RowStat* __restrict__ stats)
{
    const int lane  = threadIdx.x & 63;
    const int wid   = threadIdx.x >> 6;
    const int gwave = blockIdx.x * 4 + wid;
    const int nwaves = NB1 * 4;
    const int lane4 = lane * 4;
    const float4* base = reinterpret_cast<const float4*>(wave);

    int row = gwave;
    {
        const float4* p = base + (size_t)row * (SLEN / 4) + lane;
        // fallthrough into loop with c* preloaded
    }
    const float4* p0 = base + (size_t)row * (SLEN / 4) + lane;
    float4 c0 = p0[0], c1 = p0[64], c2 = p0[128], c3 = p0[192];

    #pragma unroll
    for (int it = 0; it < 4; ++it) {            // 32768 / 8192 = 4 rows per wave
        const int nrow = row + nwaves;
        float4 n0, n1, n2, n3;
        if (it < 3) {                           // issue next-row loads EARLY
            const float4* pn = base + (size_t)nrow * (SLEN / 4) + lane;
            n0 = pn[0]; n1 = pn[64]; n2 = pn[128]; n3 = pn[192];
        }

        float vals[16] = {c0.x,c0.y,c0.z,c0.w, c1.x,c1.y,c1.z,c1.w,
                          c2.x,c2.y,c2.z,c2.w, c3.x,c3.y,c3.z,c3.w};

        // ---- pass 1: argmax (first occurrence) + charge sum ----
        float bm = -INFINITY; int bj = SLEN;
        float csum = 0.0f;
        #pragma unroll
        for (int k = 0; k < 16; ++k) {
            const int j = (k >> 2) * 256 + lane4 + (k & 3);
            const float w = vals[k];
            csum += fmaxf(w, 0.0f);
            if (w > bm) { bm = w; bj = j; }     // j increases with k -> first max
        }
        #pragma unroll
        for (int off = 1; off < 64; off <<= 1) {
            const float ov = __shfl_xor(bm, off, 64);
            const int   oj = __shfl_xor(bj, off, 64);
            if (ov > bm || (ov == bm && oj < bj)) { bm = ov; bj = oj; }
        }
        const int   peak = bj;                  // uniform across wave
        const float amp  = bm;
        const bool  do_decay = (peak < SLEN - 20);

        // ---- pass 2 (fused): decay regression sums + rise crossings ----
        unsigned n = 0, Sk = 0, Skk = 0;
        double Sy = 0.0, Sky = 0.0;
        int i10 = SLEN, i90 = SLEN;
        const float t10 = 0.1f * amp, t90 = 0.9f * amp;
        const int pm5 = peak + 5;
        #pragma unroll
        for (int k = 0; k < 16; ++k) {
            const int j = (k >> 2) * 256 + lane4 + (k & 3);
            const float w = vals[k];
            const int kk = j - pm5;
            if (do_decay && (unsigned)kk < (unsigned)TAILW && w > 0.0f) {
                const float y = logf(w + 1e-8f);   // same numerics as r2
                n += 1u; Sk += (unsigned)kk; Skk += (unsigned)(kk * kk);
                Sy  += (double)y;
                Sky += (double)kk * (double)y;
            }
            if (j < peak) {
                if (w >= t10 && j < i10) i10 = j;
                if (w >= t90 && j < i90) i90 = j;
            }
        }
        #pragma unroll
        for (int off = 1; off < 64; off <<= 1) {
            n    += __shfl_xor(n,    off, 64);
            Sk   += __shfl_xor(Sk,   off, 64);
            Skk  += __shfl_xor(Skk,  off, 64);
            Sy   += __shfl_xor(Sy,   off, 64);
            Sky  += __shfl_xor(Sky,  off, 64);
            csum += __shfl_xor(csum, off, 64);
            i10 = min(i10, __shfl_xor(i10, off, 64));
            i90 = min(i90, __shfl_xor(i90, off, 64));
        }

        if (lane == 0) {
            RowStat st;
            st.nSk  = n | (Sk << 16);
            st.Skk  = Skk;
            st.csum = csum;
            st.pki  = ((unsigned)peak << 22) | ((unsigned)i10 << 11) | (unsigned)i90;
            st.Sy   = Sy;
            st.Sky  = Sky;
            stats[row] = st;
        }

        if (it < 3) { c0 = n0; c1 = n1; c2 = n2; c3 = n3; row = nrow; }
    }
}

// Kernel 2: one thread per row, fully parallel epilogue (CE + tau + rise +
// ratio moments), then per-block f64 reduction -> 7 partials per block.
extern "C" __global__ __launch_bounds__(256)
void physics_rowfin(const RowStat* __restrict__ stats,
                    const float* __restrict__ logits,
                    const int* __restrict__ labels,
                    const float* __restrict__ amps,
                    double* __restrict__ partials)
{
    const int r    = blockIdx.x * 256 + threadIdx.x;   // always < BROWS
    const int lane = threadIdx.x & 63;
    const int wid  = threadIdx.x >> 6;

    const RowStat st = stats[r];
    const unsigned n_u  = st.nSk & 0xFFFFu;
    const unsigned Sk_u = st.nSk >> 16;
    const int peak = (int)(st.pki >> 22);
    const int i10  = (int)((st.pki >> 11) & 0x7FFu);
    const int i90  = (int)(st.pki & 0x7FFu);

    // CE + predicted class
    const float4 l4 = reinterpret_cast<const float4*>(logits)[r];
    float lg[4] = {l4.x, l4.y, l4.z, l4.w};
    int pred = 0; float pbest = lg[0];
    #pragma unroll
    for (int c = 1; c < 4; ++c) if (lg[c] > pbest) { pbest = lg[c]; pred = c; }
    const float m = fmaxf(fmaxf(lg[0], lg[1]), fmaxf(lg[2], lg[3]));
    const float sexp = expf(lg[0] - m) + expf(lg[1] - m)
                     + expf(lg[2] - m) + expf(lg[3] - m);
    const float lse = m + logf(sexp);
    const double v0 = (double)(lse - lg[labels[r]]);

    // decay loss (f64 combine — slope/tau cancellation-sensitive)
    double v1 = 0.0, v2 = 0.0;
    if (peak < SLEN - 20 && n_u >= 5u) {
        const double dn  = (double)n_u;
        const double dSk = (double)Sk_u;
        const double num = st.Sky - dSk * st.Sy / dn;           // DT_NS factored out
        const double den = 8.0 * ((double)st.Skk - dSk * dSk / dn);
        if (den > 0.0) {
            const double slope = num / fmax(den, 1e-30);
            const double tau   = -1.0 / (slope + 1e-8);
            const double d     = tau - (double)c_decay_taus[pred];
            v1 = d * d; v2 = 1.0;
        }
    }
    // rise loss
    double v3 = 0.0, v4 = 0.0;
    if (peak >= 10 && i10 < SLEN && i90 < SLEN) {
        const float rise = (float)(i90 - i10) * 8.0f;
        const float er   = c_rise_taus[pred];
        v3 = (double)(fabsf(rise - er) / er); v4 = 1.0;
    }
    // energy ratio moments
    const double ratio = (double)st.csum / ((double)amps[r] + 1e-8);

    double v[7] = {v0, v1, v2, v3, v4, ratio, ratio * ratio};
    #pragma unroll
    for (int i = 0; i < 7; ++i) {
        #pragma unroll
        for (int off = 1; off < 64; off <<= 1)
            v[i] += __shfl_xor(v[i], off, 64);
    }
    __shared__ double sm[4][7];
    if (lane == 0) {
        #pragma unroll
        for (int i = 0; i < 7; ++i) sm[wid][i] = v[i];
    }
    __syncthreads();
    if (threadIdx.x < 7) {
        const int i = threadIdx.x;
        partials[(size_t)blockIdx.x * 7 + i] = sm[0][i] + sm[1][i] + sm[2][i] + sm[3][i];
    }
}

// Kernel 3: one wave reduces 128 partial sets and writes the 5 outputs.
extern "C" __global__ void physics_finalize(const double* __restrict__ partials,
                                            float* __restrict__ out)
{
    const int t = threadIdx.x;   // 64 threads
    double loc[7];
    #pragma unroll
    for (int i = 0; i < 7; ++i)
        loc[i] = partials[(size_t)t * 7 + i] + partials[(size_t)(t + 64) * 7 + i];
    #pragma unroll
    for (int i = 0; i < 7; ++i) {
        #pragma unroll
        for (int off = 1; off < 64; off <<= 1)
            loc[i] += __shfl_xor(loc[i], off, 64);
    }
    if (t == 0) {
        const double Bn = (double)BROWS;
        const double ce    = loc[0] / Bn;
        const double decay = (loc[2] > 0.0) ? loc[1] / fmax(loc[2], 1.0) : 0.0;
        const double rise  = (loc[4] > 0.0) ? loc[3] / fmax(loc[4], 1.0) : 0.0;
        const double var   = (loc[6] - loc[5] * loc[5] / Bn) / (Bn - 1.0);  // ddof=1
        const double total = 0.7 * ce + 0.2 * decay + 0.1 * var + 0.05 * rise;
        out[0] = (float)total; out[1] = (float)ce; out[2] = (float)decay;
        out[3] = (float)var;   out[4] = (float)rise;
    }
}

extern "C" void kernel_launch(void* const* d_in, const int* in_sizes, int n_in,
                              void* d_out, int out_size, void* d_ws, size_t ws_size,
                              hipStream_t stream) {
    const float* logits = (const float*)d_in[0];
    const int*   labels = (const int*)d_in[1];
    const float* wave   = (const float*)d_in[2];
    const float* amps   = (const float*)d_in[3];

    RowStat* stats    = (RowStat*)d_ws;                                   // 1 MiB
    double*  partials = (double*)((char*)d_ws + (size_t)BROWS * sizeof(RowStat));

    physics_rows<<<NB1, 256, 0, stream>>>(wave, stats);
    physics_rowfin<<<NB2, 256, 0, stream>>>(stats, logits, labels, amps, partials);
    physics_finalize<<<1, 64, 0, stream>>>(partials, (float*)d_out);
}

// Round 4
// 46.577 us; speedup vs baseline: 2.1761x; 1.1692x over previous
//
#include <hip/hip_runtime.h>
#include <cmath>

// Problem constants
#define BROWS 32768
#define SLEN  1024
#define TAILW 195
#define NB1   2048   // kernel1: 2048 blocks x 4 waves = 8192 waves, 4 rows/wave
#define NB2   128    // kernel2: 128 blocks x 256 threads, 1 row/thread

__device__ __constant__ float c_decay_taus[4] = {40.0f, 300.0f, 230.0f, 2.4f};
__device__ __constant__ float c_rise_taus[4]  = {5.0f, 20.0f, 10.0f, 2.0f};

// Per-row stats, 32 B. n<=195 (16b), Sk<=18915 (16b), Skk<=2451415 (exact u32),
// peak<=1023 (10b), i10/i90<=1024 (11b each).
struct alignas(16) RowStat {
    unsigned nSk;   // n | (Sk<<16)
    unsigned Skk;
    float    csum;
    unsigned pki;   // (peak<<22)|(i10<<11)|i90
    double   Sy;
    double   Sky;
};

// Kernel 1: waveform-only. One wave per row; row in 16 regs/lane; index-finding
// via ballot+SALU (no cndmask chains, no index butterflies); decay restricted
// to the <=2 register-quarters intersecting the tail window (uniform branch).
extern "C" __global__ __launch_bounds__(256, 8)
void physics_rows(const float* __restrict__ wave, RowStat* __restrict__ stats)
{
    const int lane  = threadIdx.x & 63;
    const int wid   = threadIdx.x >> 6;
    const int gwave = blockIdx.x * 4 + wid;
    const int nwaves = NB1 * 4;
    const int lane4 = lane * 4;
    const float4* base = reinterpret_cast<const float4*>(wave);

    int row = gwave;
    const float4* p0 = base + (size_t)row * (SLEN / 4) + lane;
    float4 c0 = p0[0], c1 = p0[64], c2 = p0[128], c3 = p0[192];

    #pragma unroll
    for (int it = 0; it < 4; ++it) {            // 32768 / 8192 = 4 rows per wave
        const int nrow = row + nwaves;
        float4 n0, n1, n2, n3;
        if (it < 3) {                           // issue next-row loads EARLY
            const float4* pn = base + (size_t)nrow * (SLEN / 4) + lane;
            n0 = pn[0]; n1 = pn[64]; n2 = pn[128]; n3 = pn[192];
        }

        float vals[16] = {c0.x,c0.y,c0.z,c0.w, c1.x,c1.y,c1.z,c1.w,
                          c2.x,c2.y,c2.z,c2.w, c3.x,c3.y,c3.z,c3.w};

        // ---- pass 1: value-max (v_max3 tree) + relu-sum (pairwise tree) ----
        float m0 = fmaxf(fmaxf(vals[0],  vals[1]),  vals[2]);
        float m1 = fmaxf(fmaxf(vals[3],  vals[4]),  vals[5]);
        float m2 = fmaxf(fmaxf(vals[6],  vals[7]),  vals[8]);
        float m3 = fmaxf(fmaxf(vals[9],  vals[10]), vals[11]);
        float m4 = fmaxf(fmaxf(vals[12], vals[13]), fmaxf(vals[14], vals[15]));
        float bm = fmaxf(fmaxf(fmaxf(m0, m1), m2), fmaxf(m3, m4));

        float s0 = 0.f, s1 = 0.f, s2 = 0.f, s3 = 0.f;
        #pragma unroll
        for (int k = 0; k < 16; k += 4) {
            s0 += fmaxf(vals[k],     0.0f);
            s1 += fmaxf(vals[k + 1], 0.0f);
            s2 += fmaxf(vals[k + 2], 0.0f);
            s3 += fmaxf(vals[k + 3], 0.0f);
        }
        float csum = (s0 + s1) + (s2 + s3);

        // wave max -> amp (all lanes)
        #pragma unroll
        for (int off = 1; off < 64; off <<= 1)
            bm = fmaxf(bm, __shfl_xor(bm, off, 64));
        const float amp = bm;

        // ---- peak = first index with w == amp, via ballot + scalar ffs ----
        int peak = SLEN;
        #pragma unroll
        for (int q = 0; q < 4; ++q) {
            #pragma unroll
            for (int r = 0; r < 4; ++r) {
                const unsigned long long b = __ballot(vals[q * 4 + r] == amp);
                if (b) {
                    const int cand = q * 256 + 4 * (__ffsll(b) - 1) + r;
                    peak = min(peak, cand);
                }
            }
        }
        peak = __builtin_amdgcn_readfirstlane(peak);
        const bool do_decay = (peak < SLEN - 20);
        const int  pm5 = peak + 5;

        // ---- rise crossings via ballot & scalar lane-mask (j < peak) ----
        const float t10 = 0.1f * amp, t90 = 0.9f * amp;
        int i10 = SLEN, i90 = SLEN;
        #pragma unroll
        for (int q = 0; q < 4; ++q) {
            #pragma unroll
            for (int r = 0; r < 4; ++r) {
                const int jb = q * 256 + r;          // j = jb + 4*lane
                const int d  = peak - jb;            // lanes with 4*lane < d
                if (d > 0) {                         // uniform
                    const int lc = min(64, (d + 3) >> 2);
                    const unsigned long long lm =
                        (lc >= 64) ? ~0ull : ((1ull << lc) - 1ull);
                    const float w = vals[q * 4 + r];
                    const unsigned long long b10 = __ballot(w >= t10) & lm;
                    const unsigned long long b90 = __ballot(w >= t90) & lm;
                    if (b10) i10 = min(i10, jb + 4 * (__ffsll(b10) - 1));
                    if (b90) i90 = min(i90, jb + 4 * (__ffsll(b90) - 1));
                }
            }
        }

        // ---- decay regression sums over the <=2 intersecting quarters ----
        unsigned n = 0, Sk = 0, Skk = 0;
        double Sy = 0.0, Sky = 0.0;
        if (do_decay) {                              // uniform
            #pragma unroll
            for (int q = 0; q < 4; ++q) {
                if (q * 256 + 255 >= pm5 && q * 256 <= pm5 + (TAILW - 1)) {  // uniform
                    #pragma unroll
                    for (int r = 0; r < 4; ++r) {
                        const int kk = q * 256 + lane4 + r - pm5;
                        const float w = vals[q * 4 + r];
                        if ((unsigned)kk < (unsigned)TAILW && w > 0.0f) {
                            const float y = logf(w + 1e-8f);
                            n += 1u; Sk += (unsigned)kk; Skk += (unsigned)(kk * kk);
                            Sy  += (double)y;
                            Sky += (double)kk * (double)y;
                        }
                    }
                }
            }
        }

        // ---- single butterfly for the 6 remaining quantities ----
        #pragma unroll
        for (int off = 1; off < 64; off <<= 1) {
            csum += __shfl_xor(csum, off, 64);
            n    += __shfl_xor(n,    off, 64);
            Sk   += __shfl_xor(Sk,   off, 64);
            Skk  += __shfl_xor(Skk,  off, 64);
            Sy   += __shfl_xor(Sy,   off, 64);
            Sky  += __shfl_xor(Sky,  off, 64);
        }

        if (lane == 0) {
            RowStat st;
            st.nSk  = n | (Sk << 16);
            st.Skk  = Skk;
            st.csum = csum;
            st.pki  = ((unsigned)peak << 22) | ((unsigned)i10 << 11) | (unsigned)i90;
            st.Sy   = Sy;
            st.Sky  = Sky;
            stats[row] = st;
        }

        if (it < 3) { c0 = n0; c1 = n1; c2 = n2; c3 = n3; row = nrow; }
    }
}

// Kernel 2: one thread per row, fully parallel epilogue (CE + tau + rise +
// ratio moments), then per-block f64 reduction -> 7 partials per block.
extern "C" __global__ __launch_bounds__(256)
void physics_rowfin(const RowStat* __restrict__ stats,
                    const float* __restrict__ logits,
                    const int* __restrict__ labels,
                    const float* __restrict__ amps,
                    double* __restrict__ partials)
{
    const int r    = blockIdx.x * 256 + threadIdx.x;   // always < BROWS
    const int lane = threadIdx.x & 63;
    const int wid  = threadIdx.x >> 6;

    const RowStat st = stats[r];
    const unsigned n_u  = st.nSk & 0xFFFFu;
    const unsigned Sk_u = st.nSk >> 16;
    const int peak = (int)(st.pki >> 22);
    const int i10  = (int)((st.pki >> 11) & 0x7FFu);
    const int i90  = (int)(st.pki & 0x7FFu);

    // CE + predicted class
    const float4 l4 = reinterpret_cast<const float4*>(logits)[r];
    float lg[4] = {l4.x, l4.y, l4.z, l4.w};
    int pred = 0; float pbest = lg[0];
    #pragma unroll
    for (int c = 1; c < 4; ++c) if (lg[c] > pbest) { pbest = lg[c]; pred = c; }
    const float m = fmaxf(fmaxf(lg[0], lg[1]), fmaxf(lg[2], lg[3]));
    const float sexp = expf(lg[0] - m) + expf(lg[1] - m)
                     + expf(lg[2] - m) + expf(lg[3] - m);
    const float lse = m + logf(sexp);
    const double v0 = (double)(lse - lg[labels[r]]);

    // decay loss (f64 combine — slope/tau cancellation-sensitive)
    double v1 = 0.0, v2 = 0.0;
    if (peak < SLEN - 20 && n_u >= 5u) {
        const double dn  = (double)n_u;
        const double dSk = (double)Sk_u;
        const double num = st.Sky - dSk * st.Sy / dn;           // DT_NS factored out
        const double den = 8.0 * ((double)st.Skk - dSk * dSk / dn);
        if (den > 0.0) {
            const double slope = num / fmax(den, 1e-30);
            const double tau   = -1.0 / (slope + 1e-8);
            const double d     = tau - (double)c_decay_taus[pred];
            v1 = d * d; v2 = 1.0;
        }
    }
    // rise loss
    double v3 = 0.0, v4 = 0.0;
    if (peak >= 10 && i10 < SLEN && i90 < SLEN) {
        const float rise = (float)(i90 - i10) * 8.0f;
        const float er   = c_rise_taus[pred];
        v3 = (double)(fabsf(rise - er) / er); v4 = 1.0;
    }
    // energy ratio moments
    const double ratio = (double)st.csum / ((double)amps[r] + 1e-8);

    double v[7] = {v0, v1, v2, v3, v4, ratio, ratio * ratio};
    #pragma unroll
    for (int i = 0; i < 7; ++i) {
        #pragma unroll
        for (int off = 1; off < 64; off <<= 1)
            v[i] += __shfl_xor(v[i], off, 64);
    }
    __shared__ double sm[4][7];
    if (lane == 0) {
        #pragma unroll
        for (int i = 0; i < 7; ++i) sm[wid][i] = v[i];
    }
    __syncthreads();
    if (threadIdx.x < 7) {
        const int i = threadIdx.x;
        partials[(size_t)blockIdx.x * 7 + i] = sm[0][i] + sm[1][i] + sm[2][i] + sm[3][i];
    }
}

// Kernel 3: one wave reduces 128 partial sets and writes the 5 outputs.
extern "C" __global__ void physics_finalize(const double* __restrict__ partials,
                                            float* __restrict__ out)
{
    const int t = threadIdx.x;   // 64 threads
    double loc[7];
    #pragma unroll
    for (int i = 0; i < 7; ++i)
        loc[i] = partials[(size_t)t * 7 + i] + partials[(size_t)(t + 64) * 7 + i];
    #pragma unroll
    for (int i = 0; i < 7; ++i) {
        #pragma unroll
        for (int off = 1; off < 64; off <<= 1)
            loc[i] += __shfl_xor(loc[i], off, 64);
    }
    if (t == 0) {
        const double Bn = (double)BROWS;
        const double ce    = loc[0] / Bn;
        const double decay = (loc[2] > 0.0) ? loc[1] / fmax(loc[2], 1.0) : 0.0;
        const double rise  = (loc[4] > 0.0) ? loc[3] / fmax(loc[4], 1.0) : 0.0;
        const double var   = (loc[6] - loc[5] * loc[5] / Bn) / (Bn - 1.0);  // ddof=1
        const double total = 0.7 * ce + 0.2 * decay + 0.1 * var + 0.05 * rise;
        out[0] = (float)total; out[1] = (float)ce; out[2] = (float)decay;
        out[3] = (float)var;   out[4] = (float)rise;
    }
}

extern "C" void kernel_launch(void* const* d_in, const int* in_sizes, int n_in,
                              void* d_out, int out_size, void* d_ws, size_t ws_size,
                              hipStream_t stream) {
    const float* logits = (const float*)d_in[0];
    const int*   labels = (const int*)d_in[1];
    const float* wave   = (const float*)d_in[2];
    const float* amps   = (const float*)d_in[3];

    RowStat* stats    = (RowStat*)d_ws;                                   // 1 MiB
    double*  partials = (double*)((char*)d_ws + (size_t)BROWS * sizeof(RowStat));

    physics_rows<<<NB1, 256, 0, stream>>>(wave, stats);
    physics_rowfin<<<NB2, 256, 0, stream>>>(stats, logits, labels, amps, partials);
    physics_finalize<<<1, 64, 0, stream>>>(partials, (float*)d_out);
}

// Round 5
// 46.131 us; speedup vs baseline: 2.1972x; 1.0097x over previous
//
#include <hip/hip_runtime.h>
#include <cmath>

// Problem constants
#define BROWS 32768
#define SLEN  1024
#define TAILW 195
#define NB1   2048   // kernel1: 2048 blocks x 4 waves = 8192 waves, 4 rows/wave
#define NB2   128    // kernel2: 128 blocks x 256 threads, 1 row/thread

__device__ __constant__ float c_decay_taus[4] = {40.0f, 300.0f, 230.0f, 2.4f};
__device__ __constant__ float c_rise_taus[4]  = {5.0f, 20.0f, 10.0f, 2.0f};

// Per-row stats, 32 B. n<=195 (16b), Sk<=18915 (16b), Skk<=2451415 (exact u32),
// peak<=1023 (10b), i10/i90<=1024 (11b each).
struct alignas(16) RowStat {
    unsigned nSk;   // n | (Sk<<16)
    unsigned Skk;
    float    csum;
    unsigned pki;   // (peak<<22)|(i10<<11)|i90
    double   Sy;
    double   Sky;
};

// Kernel 1: waveform-only. One wave per row; row in 16 regs/lane; index-finding
// via ballot+SALU; decay restricted to the <=2 quarters intersecting the tail
// window; native v_log_f32 (__logf) for the tail log (f64 accumulation keeps
// the slope/tau combine accurate); amp+csum butterflies interleaved.
extern "C" __global__ __launch_bounds__(256, 8)
void physics_rows(const float* __restrict__ wave, RowStat* __restrict__ stats)
{
    const int lane  = threadIdx.x & 63;
    const int wid   = threadIdx.x >> 6;
    const int gwave = blockIdx.x * 4 + wid;
    const int nwaves = NB1 * 4;
    const int lane4 = lane * 4;
    const float4* base = reinterpret_cast<const float4*>(wave);

    int row = gwave;
    const float4* p0 = base + (size_t)row * (SLEN / 4) + lane;
    float4 c0 = p0[0], c1 = p0[64], c2 = p0[128], c3 = p0[192];

    #pragma unroll
    for (int it = 0; it < 4; ++it) {            // 32768 / 8192 = 4 rows per wave
        const int nrow = row + nwaves;
        float4 n0, n1, n2, n3;
        if (it < 3) {                           // issue next-row loads EARLY
            const float4* pn = base + (size_t)nrow * (SLEN / 4) + lane;
            n0 = pn[0]; n1 = pn[64]; n2 = pn[128]; n3 = pn[192];
        }

        float vals[16] = {c0.x,c0.y,c0.z,c0.w, c1.x,c1.y,c1.z,c1.w,
                          c2.x,c2.y,c2.z,c2.w, c3.x,c3.y,c3.z,c3.w};

        // ---- pass 1: value-max (v_max3 tree) + relu-sum ----
        float m0 = fmaxf(fmaxf(vals[0],  vals[1]),  vals[2]);
        float m1 = fmaxf(fmaxf(vals[3],  vals[4]),  vals[5]);
        float m2 = fmaxf(fmaxf(vals[6],  vals[7]),  vals[8]);
        float m3 = fmaxf(fmaxf(vals[9],  vals[10]), vals[11]);
        float m4 = fmaxf(fmaxf(vals[12], vals[13]), fmaxf(vals[14], vals[15]));
        float bm = fmaxf(fmaxf(fmaxf(m0, m1), m2), fmaxf(m3, m4));

        float s0 = 0.f, s1 = 0.f, s2 = 0.f, s3 = 0.f;
        #pragma unroll
        for (int k = 0; k < 16; k += 4) {
            s0 += fmaxf(vals[k],     0.0f);
            s1 += fmaxf(vals[k + 1], 0.0f);
            s2 += fmaxf(vals[k + 2], 0.0f);
            s3 += fmaxf(vals[k + 3], 0.0f);
        }
        float csum = (s0 + s1) + (s2 + s3);

        // ---- interleaved butterflies: amp (max) + csum (sum) ----
        #pragma unroll
        for (int off = 1; off < 64; off <<= 1) {
            bm   = fmaxf(bm, __shfl_xor(bm, off, 64));
            csum += __shfl_xor(csum, off, 64);
        }
        const float amp = bm;

        // ---- peak = first index with w == amp, via ballot + scalar ffs ----
        // any hit in quarter q beats all of quarter q+1 -> early exit
        int peak = SLEN;
        #pragma unroll
        for (int q = 0; q < 4; ++q) {
            bool found = false;
            #pragma unroll
            for (int r = 0; r < 4; ++r) {
                const unsigned long long b = __ballot(vals[q * 4 + r] == amp);
                if (b) {
                    peak = min(peak, q * 256 + 4 * (__ffsll(b) - 1) + r);
                    found = true;
                }
            }
            if (found) break;
        }
        peak = __builtin_amdgcn_readfirstlane(peak);
        const bool do_decay = (peak < SLEN - 20);
        const int  pm5 = peak + 5;

        // ---- rise crossings via ballot & scalar lane-mask (j < peak) ----
        const float t10 = 0.1f * amp, t90 = 0.9f * amp;
        int i10 = SLEN, i90 = SLEN;
        #pragma unroll
        for (int q = 0; q < 4; ++q) {
            #pragma unroll
            for (int r = 0; r < 4; ++r) {
                const int jb = q * 256 + r;          // j = jb + 4*lane
                const int d  = peak - jb;            // lanes with 4*lane < d
                if (d > 0) {                         // uniform
                    const int lc = min(64, (d + 3) >> 2);
                    const unsigned long long lm =
                        (lc >= 64) ? ~0ull : ((1ull << lc) - 1ull);
                    const float w = vals[q * 4 + r];
                    const unsigned long long b10 = __ballot(w >= t10) & lm;
                    const unsigned long long b90 = __ballot(w >= t90) & lm;
                    if (b10) i10 = min(i10, jb + 4 * (__ffsll(b10) - 1));
                    if (b90) i90 = min(i90, jb + 4 * (__ffsll(b90) - 1));
                }
            }
        }

        // ---- decay regression sums over the <=2 intersecting quarters ----
        unsigned nSk_p = 0, Skk = 0;     // nSk_p = n | (Sk<<8): n<=195, Sk<=18915
        double Sy = 0.0, Sky = 0.0;
        if (do_decay) {                              // uniform
            #pragma unroll
            for (int q = 0; q < 4; ++q) {
                if (q * 256 + 255 >= pm5 && q * 256 <= pm5 + (TAILW - 1)) {  // uniform
                    #pragma unroll
                    for (int r = 0; r < 4; ++r) {
                        const int kk = q * 256 + lane4 + r - pm5;
                        const float w = vals[q * 4 + r];
                        if ((unsigned)kk < (unsigned)TAILW && w > 0.0f) {
                            const float y = __logf(w + 1e-8f);   // native v_log_f32
                            nSk_p += 1u + ((unsigned)kk << 8);
                            Skk   += (unsigned)(kk * kk);
                            Sy  += (double)y;
                            Sky += (double)kk * (double)y;
                        }
                    }
                }
            }
        }

        // ---- single butterfly for the 4 remaining quantities ----
        #pragma unroll
        for (int off = 1; off < 64; off <<= 1) {
            nSk_p += __shfl_xor(nSk_p, off, 64);
            Skk   += __shfl_xor(Skk,   off, 64);
            Sy    += __shfl_xor(Sy,    off, 64);
            Sky   += __shfl_xor(Sky,   off, 64);
        }

        if (lane == 0) {
            RowStat st;
            st.nSk  = (nSk_p & 0xFFu) | ((nSk_p >> 8) << 16);  // -> n | Sk<<16
            st.Skk  = Skk;
            st.csum = csum;
            st.pki  = ((unsigned)peak << 22) | ((unsigned)i10 << 11) | (unsigned)i90;
            st.Sy   = Sy;
            st.Sky  = Sky;
            stats[row] = st;
        }

        if (it < 3) { c0 = n0; c1 = n1; c2 = n2; c3 = n3; row = nrow; }
    }
}

// Kernel 2: one thread per row, fully parallel epilogue (CE + tau + rise +
// ratio moments), then per-block f64 reduction -> 7 partials per block.
extern "C" __global__ __launch_bounds__(256)
void physics_rowfin(const RowStat* __restrict__ stats,
                    const float* __restrict__ logits,
                    const int* __restrict__ labels,
                    const float* __restrict__ amps,
                    double* __restrict__ partials)
{
    const int r    = blockIdx.x * 256 + threadIdx.x;   // always < BROWS
    const int lane = threadIdx.x & 63;
    const int wid  = threadIdx.x >> 6;

    const RowStat st = stats[r];
    const unsigned n_u  = st.nSk & 0xFFFFu;
    const unsigned Sk_u = st.nSk >> 16;
    const int peak = (int)(st.pki >> 22);
    const int i10  = (int)((st.pki >> 11) & 0x7FFu);
    const int i90  = (int)(st.pki & 0x7FFu);

    // CE + predicted class (library expf/logf — accuracy matters here)
    const float4 l4 = reinterpret_cast<const float4*>(logits)[r];
    float lg[4] = {l4.x, l4.y, l4.z, l4.w};
    int pred = 0; float pbest = lg[0];
    #pragma unroll
    for (int c = 1; c < 4; ++c) if (lg[c] > pbest) { pbest = lg[c]; pred = c; }
    const float m = fmaxf(fmaxf(lg[0], lg[1]), fmaxf(lg[2], lg[3]));
    const float sexp = expf(lg[0] - m) + expf(lg[1] - m)
                     + expf(lg[2] - m) + expf(lg[3] - m);
    const float lse = m + logf(sexp);
    const double v0 = (double)(lse - lg[labels[r]]);

    // decay loss (f64 combine — slope/tau cancellation-sensitive)
    double v1 = 0.0, v2 = 0.0;
    if (peak < SLEN - 20 && n_u >= 5u) {
        const double dn  = (double)n_u;
        const double dSk = (double)Sk_u;
        const double num = st.Sky - dSk * st.Sy / dn;           // DT_NS factored out
        const double den = 8.0 * ((double)st.Skk - dSk * dSk / dn);
        if (den > 0.0) {
            const double slope = num / fmax(den, 1e-30);
            const double tau   = -1.0 / (slope + 1e-8);
            const double d     = tau - (double)c_decay_taus[pred];
            v1 = d * d; v2 = 1.0;
        }
    }
    // rise loss
    double v3 = 0.0, v4 = 0.0;
    if (peak >= 10 && i10 < SLEN && i90 < SLEN) {
        const float rise = (float)(i90 - i10) * 8.0f;
        const float er   = c_rise_taus[pred];
        v3 = (double)(fabsf(rise - er) / er); v4 = 1.0;
    }
    // energy ratio moments
    const double ratio = (double)st.csum / ((double)amps[r] + 1e-8);

    double v[7] = {v0, v1, v2, v3, v4, ratio, ratio * ratio};
    #pragma unroll
    for (int i = 0; i < 7; ++i) {
        #pragma unroll
        for (int off = 1; off < 64; off <<= 1)
            v[i] += __shfl_xor(v[i], off, 64);
    }
    __shared__ double sm[4][7];
    if (lane == 0) {
        #pragma unroll
        for (int i = 0; i < 7; ++i) sm[wid][i] = v[i];
    }
    __syncthreads();
    if (threadIdx.x < 7) {
        const int i = threadIdx.x;
        partials[(size_t)blockIdx.x * 7 + i] = sm[0][i] + sm[1][i] + sm[2][i] + sm[3][i];
    }
}

// Kernel 3: one wave reduces 128 partial sets and writes the 5 outputs.
extern "C" __global__ void physics_finalize(const double* __restrict__ partials,
                                            float* __restrict__ out)
{
    const int t = threadIdx.x;   // 64 threads
    double loc[7];
    #pragma unroll
    for (int i = 0; i < 7; ++i)
        loc[i] = partials[(size_t)t * 7 + i] + partials[(size_t)(t + 64) * 7 + i];
    #pragma unroll
    for (int i = 0; i < 7; ++i) {
        #pragma unroll
        for (int off = 1; off < 64; off <<= 1)
            loc[i] += __shfl_xor(loc[i], off, 64);
    }
    if (t == 0) {
        const double Bn = (double)BROWS;
        const double ce    = loc[0] / Bn;
        const double decay = (loc[2] > 0.0) ? loc[1] / fmax(loc[2], 1.0) : 0.0;
        const double rise  = (loc[4] > 0.0) ? loc[3] / fmax(loc[4], 1.0) : 0.0;
        const double var   = (loc[6] - loc[5] * loc[5] / Bn) / (Bn - 1.0);  // ddof=1
        const double total = 0.7 * ce + 0.2 * decay + 0.1 * var + 0.05 * rise;
        out[0] = (float)total; out[1] = (float)ce; out[2] = (float)decay;
        out[3] = (float)var;   out[4] = (float)rise;
    }
}

extern "C" void kernel_launch(void* const* d_in, const int* in_sizes, int n_in,
                              void* d_out, int out_size, void* d_ws, size_t ws_size,
                              hipStream_t stream) {
    const float* logits = (const float*)d_in[0];
    const int*   labels = (const int*)d_in[1];
    const float* wave   = (const float*)d_in[2];
    const float* amps   = (const float*)d_in[3];

    RowStat* stats    = (RowStat*)d_ws;                                   // 1 MiB
    double*  partials = (double*)((char*)d_ws + (size_t)BROWS * sizeof(RowStat));

    physics_rows<<<NB1, 256, 0, stream>>>(wave, stats);
    physics_rowfin<<<NB2, 256, 0, stream>>>(stats, logits, labels, amps, partials);
    physics_finalize<<<1, 64, 0, stream>>>(partials, (float*)d_out);
}